// Round 1
// baseline (220.346 us; speedup 1.0000x reference)
//
#include <hip/hip_runtime.h>
#include <math.h>

#define B_    256
#define C_    22
#define T_    1000
#define NB_   6
#define E_    6
#define MNB_  48
#define POOL_ 125
#define TP_   8
#define NC_   9
#define FEAT_ 384   // MNB_*TP_

// ---------------------------------------------------------------------------
// Stage 1: FIR bank -> {conv3,conv5,conv7 concat + triple-mean} -> BN -> ReLU
//          -> sconv (sum over C) -> pooled hp (B,NB,8) and gate-mean gm (B,NB)
// One block per (b, nb). 256 threads; thread handles 4 consecutive t.
// ---------------------------------------------------------------------------
__global__ __launch_bounds__(256) void fb_stage1(
    const float* __restrict__ x,
    const float* __restrict__ fir,
    const float* __restrict__ w3,
    const float* __restrict__ w5,
    const float* __restrict__ w7,
    const float* __restrict__ bn_g, const float* __restrict__ bn_b,
    const float* __restrict__ bn_m, const float* __restrict__ bn_v,
    const float* __restrict__ sconv_w,
    float* __restrict__ hp, float* __restrict__ gm)
{
    const int b   = blockIdx.x / NB_;
    const int nb  = blockIdx.x % NB_;
    const int tid = threadIdx.x;

    __shared__ float xs[1020];    // x row with 10-halo each side (zeros)
    __shared__ float xbs[1008];   // xb[p] at xbs[4+p]; zeros at [0..3],[1004..1007]
    __shared__ float hrow[1000];
    __shared__ float firs[21];
    __shared__ float w3s[3], w5s[5], w7s[7];
    __shared__ float sws[22];
    __shared__ float sbn[2];
    __shared__ float psum[8];

    if (tid < 21)                 firs[tid]      = fir[nb*21 + tid];
    if (tid >= 32  && tid < 35)   w3s[tid-32]    = w3[nb*3 + (tid-32)];
    if (tid >= 64  && tid < 69)   w5s[tid-64]    = w5[nb*5 + (tid-64)];
    if (tid >= 96  && tid < 103)  w7s[tid-96]    = w7[nb*7 + (tid-96)];
    if (tid >= 128 && tid < 150)  sws[tid-128]   = sconv_w[nb*C_ + (tid-128)];
    if (tid == 160) {
        float sc = bn_g[nb] * rsqrtf(bn_v[nb] + 1e-5f);
        sbn[0] = sc;
        sbn[1] = bn_b[nb] - bn_m[nb] * sc;
    }
    if (tid < 10) { xs[tid] = 0.f; xs[1010 + tid] = 0.f; }
    if (tid >= 192 && tid < 196) { xbs[tid-192] = 0.f; xbs[1004 + (tid-192)] = 0.f; }

    const int  t0       = tid * 4;                 // first output t of this thread
    const bool active   = (t0 < T_);
    const bool crossing = (t0 == 332) || (t0 == 664); // owns t=333 / t=666

    __syncthreads();   // weights visible

    // Unified 9-tap summed kernel: h[t]*3 = sum_{mm=0..8} xb[q-3+mm]*kreg[mm],
    // q = 3t - 1000*r.  kreg[mm] = ws_r[mm-3+pk], ws_r[m] = w[m]+w[m-1]+w[m-2].
    int r = 0;
    if (active) { if (3*t0 >= 2000) r = 2; else if (3*t0 >= 1000) r = 1; }
    float kreg[9];
    {
        const float* wk = (r == 0) ? w3s : (r == 1 ? w5s : w7s);
        const int k  = (r == 0) ? 3 : (r == 1 ? 5 : 7);
        const int pk = k >> 1;
        #pragma unroll
        for (int mm = 0; mm < 9; ++mm) {
            int m = mm - 3 + pk;
            float s = 0.f;
            for (int d = 0; d < 3; ++d) {
                int wi = m - d;
                if (wi >= 0 && wi < k) s += wk[wi];
            }
            kreg[mm] = (active && !crossing) ? s : 0.f;
        }
    }

    float acc0 = 0.f, acc1 = 0.f, acc2 = 0.f, acc3 = 0.f;
    const float inv3 = 1.f / 3.f;

    for (int c = 0; c < C_; ++c) {
        __syncthreads();
        for (int t = tid; t < T_; t += 256)
            xs[10 + t] = x[(b*C_ + c)*T_ + t];
        __syncthreads();

        if (active) {
            // FIR: 4 outputs from a 24-float register window
            float xw[24];
            #pragma unroll
            for (int k = 0; k < 24; ++k) xw[k] = xs[t0 + k];
            float v0 = 0.f, v1 = 0.f, v2 = 0.f, v3 = 0.f;
            #pragma unroll
            for (int k = 0; k < 21; ++k) {
                float f = firs[k];
                v0 += xw[k]     * f;
                v1 += xw[k + 1] * f;
                v2 += xw[k + 2] * f;
                v3 += xw[k + 3] * f;
            }
            *(float4*)&xbs[4 + t0] = make_float4(v0, v1, v2, v3);
        }
        __syncthreads();

        if (active) {
            const float sc = sbn[0], bi = sbn[1], sw = sws[c];
            if (!crossing) {
                const int base = 3*t0 - 1000*r - 3;
                float xw2[18];
                #pragma unroll
                for (int m = 0; m < 18; ++m) xw2[m] = xbs[4 + base + m];
                float hv[4];
                #pragma unroll
                for (int o = 0; o < 4; ++o) {
                    float s = 0.f;
                    #pragma unroll
                    for (int mm = 0; mm < 9; ++mm) s += xw2[3*o + mm] * kreg[mm];
                    hv[o] = fmaxf(fmaf(s * inv3, sc, bi), 0.f) * sw;
                }
                acc0 += hv[0]; acc1 += hv[1]; acc2 += hv[2]; acc3 += hv[3];
            } else {
                // exact scalar path for the two threads spanning t=333 / t=666
                float hv[4];
                #pragma unroll
                for (int o = 0; o < 4; ++o) {
                    const int t = t0 + o;
                    float s3 = 0.f;
                    for (int j = 0; j < 3; ++j) {
                        const int f = 3*t + j;
                        float v = 0.f;
                        if (f < 1000) {
                            for (int k = 0; k < 3; ++k) v += xbs[4 + f + k - 1] * w3s[k];
                        } else if (f < 2000) {
                            const int p = f - 1000;
                            for (int k = 0; k < 5; ++k) v += xbs[4 + p + k - 2] * w5s[k];
                        } else {
                            const int p = f - 2000;
                            for (int k = 0; k < 7; ++k) v += xbs[4 + p + k - 3] * w7s[k];
                        }
                        s3 += v;
                    }
                    hv[o] = fmaxf(fmaf(s3 * inv3, sc, bi), 0.f) * sw;
                }
                acc0 += hv[0]; acc1 += hv[1]; acc2 += hv[2]; acc3 += hv[3];
            }
        }
    }

    __syncthreads();
    if (active) *(float4*)&hrow[t0] = make_float4(acc0, acc1, acc2, acc3);
    __syncthreads();

    if (tid < TP_) {
        float s = 0.f;
        for (int j = 0; j < POOL_; ++j) s += hrow[tid*POOL_ + j];
        psum[tid] = s;
        hp[(b*NB_ + nb)*TP_ + tid] = s * (1.f / POOL_);
    }
    __syncthreads();
    if (tid == 0) {
        float s = 0.f;
        for (int p = 0; p < TP_; ++p) s += psum[p];
        gm[b*NB_ + nb] = s * (1.f / T_);
    }
}

// ---------------------------------------------------------------------------
// Stage 2: gate (softmax + top-3 + renorm), experts + EBN + ReLU + mix,
//          FC + log_softmax.  One block (64 thr) per batch element.
// ---------------------------------------------------------------------------
__global__ __launch_bounds__(64) void fb_stage2(
    const float* __restrict__ hp, const float* __restrict__ gm,
    const float* __restrict__ gate_w, const float* __restrict__ gate_b,
    const float* __restrict__ exp_w,  const float* __restrict__ exp_b,
    const float* __restrict__ ebn_g,  const float* __restrict__ ebn_b,
    const float* __restrict__ ebn_m,  const float* __restrict__ ebn_v,
    const float* __restrict__ fc_w,   const float* __restrict__ fc_b,
    float* __restrict__ feats_out, float* __restrict__ logp_out)
{
    const int b   = blockIdx.x;
    const int tid = threadIdx.x;

    __shared__ float lg[MNB_];
    __shared__ float gsh[E_];
    __shared__ float hps[MNB_];
    __shared__ float fsh[FEAT_];
    __shared__ float lo[NC_];

    if (tid < MNB_) {
        hps[tid] = hp[b*MNB_ + tid];
        float s = gate_b[tid];
        for (int c = 0; c < NB_; ++c) s += gm[b*NB_ + c] * gate_w[tid*NB_ + c];
        lg[tid] = s;
    }
    __syncthreads();

    if (tid == 0) {
        float mx = lg[0];
        for (int i = 1; i < MNB_; ++i) mx = fmaxf(mx, lg[i]);
        for (int i = 0; i < MNB_; ++i) lg[i] = expf(lg[i] - mx);
        int i1 = 0, i2 = -1, i3 = -1;
        float b1 = -1.f, b2 = -1.f, b3 = -1.f;
        for (int i = 0; i < MNB_; ++i) if (lg[i] > b1) { b1 = lg[i]; i1 = i; }
        for (int i = 0; i < MNB_; ++i) if (i != i1 && lg[i] > b2) { b2 = lg[i]; i2 = i; }
        for (int i = 0; i < MNB_; ++i) if (i != i1 && i != i2 && lg[i] > b3) { b3 = lg[i]; i3 = i; }
        const float s3 = lg[i1] + lg[i2] + lg[i3];
        for (int j = 0; j < E_; ++j) gsh[j] = 0.f;
        if (i1 < E_) gsh[i1] = lg[i1] / s3;
        if (i2 < E_) gsh[i2] = lg[i2] / s3;
        if (i3 < E_) gsh[i3] = lg[i3] / s3;
    }
    __syncthreads();

    #pragma unroll
    for (int rr = 0; rr < FEAT_/64; ++rr) {
        const int idx = tid + rr*64;        // 0..383
        const int o = idx >> 3, p = idx & 7;
        float outv = 0.f;
        #pragma unroll
        for (int e = 0; e < E_; ++e) {
            const int eo = e*MNB_ + o;
            float acc = exp_b[eo];
            #pragma unroll
            for (int c = 0; c < NB_; ++c)
                acc += hps[c*TP_ + p] * exp_w[eo*NB_ + c];
            const float esc = ebn_g[eo] * rsqrtf(ebn_v[eo] + 1e-5f);
            float v = fmaf(acc - ebn_m[eo], esc, ebn_b[eo]);
            v = fmaxf(v, 0.f);
            outv += gsh[e] * v;
        }
        fsh[idx] = outv;
        feats_out[b*FEAT_ + idx] = outv;
    }
    __syncthreads();

    if (tid < NC_) {
        float s = fc_b[tid];
        for (int i = 0; i < FEAT_; ++i) s += fsh[i] * fc_w[tid*FEAT_ + i];
        lo[tid] = s;
    }
    __syncthreads();

    if (tid == 0) {
        float mx = lo[0];
        for (int k = 1; k < NC_; ++k) mx = fmaxf(mx, lo[k]);
        float Z = 0.f;
        for (int k = 0; k < NC_; ++k) Z += expf(lo[k] - mx);
        const float lse = mx + logf(Z);
        for (int k = 0; k < NC_; ++k) logp_out[b*NC_ + k] = lo[k] - lse;
    }
}

extern "C" void kernel_launch(void* const* d_in, const int* in_sizes, int n_in,
                              void* d_out, int out_size, void* d_ws, size_t ws_size,
                              hipStream_t stream) {
    const float* x       = (const float*)d_in[0];
    const float* fir     = (const float*)d_in[1];
    const float* w3      = (const float*)d_in[2];
    const float* w5      = (const float*)d_in[3];
    const float* w7      = (const float*)d_in[4];
    const float* bn1_g   = (const float*)d_in[5];
    const float* bn1_b   = (const float*)d_in[6];
    const float* bn1_m   = (const float*)d_in[7];
    const float* bn1_v   = (const float*)d_in[8];
    const float* sconv_w = (const float*)d_in[9];
    const float* gate_w  = (const float*)d_in[10];
    const float* gate_b  = (const float*)d_in[11];
    const float* exp_w   = (const float*)d_in[12];
    const float* exp_b   = (const float*)d_in[13];
    const float* ebn_g   = (const float*)d_in[14];
    const float* ebn_b   = (const float*)d_in[15];
    const float* ebn_m   = (const float*)d_in[16];
    const float* ebn_v   = (const float*)d_in[17];
    const float* fc_w    = (const float*)d_in[18];
    const float* fc_b    = (const float*)d_in[19];

    float* out       = (float*)d_out;
    float* feats_out = out;                     // (256, 384)
    float* logp_out  = out + B_ * FEAT_;        // (256, 9)

    float* hp = (float*)d_ws;                   // (256, 48)
    float* gmv = hp + B_ * MNB_;                // (256, 6)

    fb_stage1<<<B_ * NB_, 256, 0, stream>>>(x, fir, w3, w5, w7,
                                            bn1_g, bn1_b, bn1_m, bn1_v,
                                            sconv_w, hp, gmv);
    fb_stage2<<<B_, 64, 0, stream>>>(hp, gmv, gate_w, gate_b,
                                     exp_w, exp_b, ebn_g, ebn_b, ebn_m, ebn_v,
                                     fc_w, fc_b, feats_out, logp_out);
}